// Round 1
// baseline (228.899 us; speedup 1.0000x reference)
//
#include <hip/hip_runtime.h>

// Problem constants (from reference): patches [B,N,L] fp32, masked_indices [B,M] int
constexpr int B = 256;
constexpr int N = 1024;
constexpr int L = 128;   // row = 128 floats = 32 float4 = 512 B
constexpr int M = 512;

// Kernel 1: scatter flags — flag[b*N + idx] = 1 for each (b, m).
// Duplicates write the same value; no hazard.
__global__ void flag_kernel(const int* __restrict__ idx,
                            unsigned char* __restrict__ flags) {
    int i = blockIdx.x * blockDim.x + threadIdx.x;
    if (i < B * M) {
        int b = i >> 9;          // i / M, M = 512
        int n = idx[i];
        flags[b * N + n] = 1;
    }
}

// Kernel 2: fused copy-or-linspace. One thread per float4; 32 threads per row.
// Flagged rows: read only row[0] and row[127] (wave-broadcast loads), compute
// linspace. Unflagged rows: float4 copy.
__global__ void main_kernel(const float* __restrict__ in,
                            const unsigned char* __restrict__ flags,
                            float* __restrict__ out) {
    int t = blockIdx.x * blockDim.x + threadIdx.x;  // total threads = B*N*32
    int row  = t >> 5;      // global row in [0, B*N)
    int quad = t & 31;      // which float4 within the row
    const float* rowp = in + (size_t)row * L;
    float* outp = out + (size_t)row * L + quad * 4;

    if (flags[row]) {
        float s = rowp[0];
        float e = rowp[L - 1];
        float d = e - s;
        int l0 = quad * 4;
        // match reference: start + (end-start) * (l / (L-1))
        float4 v;
        v.x = s + d * ((float)(l0 + 0) * (1.0f / 127.0f));
        v.y = s + d * ((float)(l0 + 1) * (1.0f / 127.0f));
        v.z = s + d * ((float)(l0 + 2) * (1.0f / 127.0f));
        v.w = s + d * ((float)(l0 + 3) * (1.0f / 127.0f));
        *(float4*)outp = v;
    } else {
        *(float4*)outp = *(const float4*)(rowp + quad * 4);
    }
}

extern "C" void kernel_launch(void* const* d_in, const int* in_sizes, int n_in,
                              void* d_out, int out_size, void* d_ws, size_t ws_size,
                              hipStream_t stream) {
    const float* patches = (const float*)d_in[0];
    const int* masked    = (const int*)d_in[1];
    float* out           = (float*)d_out;
    unsigned char* flags = (unsigned char*)d_ws;   // B*N bytes = 256 KiB

    // ws is re-poisoned to 0xAA before every launch — zero the flags.
    hipMemsetAsync(flags, 0, (size_t)B * N, stream);

    {
        int total = B * M;                  // 131072
        int block = 256;
        int grid = (total + block - 1) / block;
        flag_kernel<<<grid, block, 0, stream>>>(masked, flags);
    }
    {
        long long total = (long long)B * N * 32;  // 8,388,608 threads
        int block = 256;
        long long grid = (total + block - 1) / block;
        main_kernel<<<(int)grid, block, 0, stream>>>(patches, flags, out);
    }
}